// Round 6
// baseline (1099.778 us; speedup 1.0000x reference)
//
#include <hip/hip_runtime.h>
#include <hip/hip_bf16.h>
#include <hip/hip_cooperative_groups.h>

namespace cg = cooperative_groups;

#define DIM 4096
#define HROWS 54
#define HSZ (HROWS * DIM)   // 221184
#define SPLITK 8
#define KSLICE 512

typedef __attribute__((ext_vector_type(4))) float  f32x4;
typedef __attribute__((ext_vector_type(8))) short  s16x8;
typedef __attribute__((ext_vector_type(4))) short  s16x4;

__device__ __forceinline__ short f2bf(float f) {
    union { __hip_bfloat16 h; short s; } u;
    u.h = __float2bfloat16(f);
    return u.s;
}
__device__ __forceinline__ float bf2f(short s) {
    union { __hip_bfloat16 h; short s; } u;
    u.s = s;
    return __bfloat162float(u.h);
}
__device__ __forceinline__ float leaky(float x) { return x > 0.f ? x : 0.01f * x; }

__device__ __forceinline__ void split8(const f32x4& c0, const f32x4& c1,
                                       s16x8& h, s16x8& l) {
#pragma unroll
    for (int j = 0; j < 4; ++j) {
        short h0 = f2bf(c0[j]); h[j]     = h0; l[j]     = f2bf(c0[j] - bf2f(h0));
        short h1 = f2bf(c1[j]); h[4 + j] = h1; l[4 + j] = f2bf(c1[j] - bf2f(h1));
    }
}

// ---------------------------------------------------------------------------
// prep task t in [0,1024): bf16 split of concept_embed, zero pads, trig tables
// ---------------------------------------------------------------------------
__device__ __forceinline__ void prep_dev(const float* __restrict__ ce,
                                         const float* __restrict__ edge,
                                         short* __restrict__ xh, short* __restrict__ xl,
                                         short* __restrict__ hbh, short* __restrict__ hbl,
                                         float* __restrict__ er, float* __restrict__ ei,
                                         int t, int tid)
{
    const int idx = t * 256 + tid;
    const int row = idx >> 12;
    if (row < HROWS) {
        const float v = ce[idx];
        const short h = f2bf(v);
        xh[idx] = h; xl[idx] = f2bf(v - bf2f(h));
    } else {
        xh[idx] = 0; xl[idx] = 0; hbh[idx] = 0; hbl[idx] = 0;
    }
    if (idx < 3 * 2048) {
        const float e = edge[idx];
        er[idx] = cosf(e);
        ei[idx] = sinf(e);
    }
}

// ---------------------------------------------------------------------------
// GEMM task t in [0,512): out[m,n] = sum_k A[m,k]*W[n,k]. A bf16 hi/lo [64][4096],
// W f32 streamed. Barrier-free, LDS-free. t = (ks<<6)|nb.
// ---------------------------------------------------------------------------
__device__ __forceinline__ void gemm_dev(const short* __restrict__ Ah,
                                         const short* __restrict__ Al,
                                         const float* __restrict__ W,
                                         float* __restrict__ outp,
                                         int t, int tid)
{
    const int lane = tid & 63;
    const int wv   = tid >> 6;
    const int nb   = t & 63;
    const int ks   = t >> 6;         // 0..7
    const int l15  = lane & 15;
    const int lk8  = lane >> 4;

    const int ncol = nb * 64 + wv * 16 + l15;
    const int k0   = ks * KSLICE + lk8 * 8;
    const float* wp = W + (size_t)ncol * DIM + k0;

    const short* ah0 = Ah + (size_t)(0 * 16 + l15) * DIM + k0;
    const short* ah1 = Ah + (size_t)(1 * 16 + l15) * DIM + k0;
    const short* ah2 = Ah + (size_t)(2 * 16 + l15) * DIM + k0;
    const short* ah3 = Ah + (size_t)(3 * 16 + l15) * DIM + k0;
    const short* al0 = Al + (size_t)(0 * 16 + l15) * DIM + k0;
    const short* al1 = Al + (size_t)(1 * 16 + l15) * DIM + k0;
    const short* al2 = Al + (size_t)(2 * 16 + l15) * DIM + k0;
    const short* al3 = Al + (size_t)(3 * 16 + l15) * DIM + k0;

    f32x4 acc0 = {0.f,0.f,0.f,0.f}, acc1 = {0.f,0.f,0.f,0.f};
    f32x4 acc2 = {0.f,0.f,0.f,0.f}, acc3 = {0.f,0.f,0.f,0.f};

#pragma unroll
    for (int kb = 0; kb < 8; ++kb) {
        const int ko = kb * 64;
        const f32x4 b00 = *(const f32x4*)(wp + ko);
        const f32x4 b01 = *(const f32x4*)(wp + ko + 4);
        const f32x4 b10 = *(const f32x4*)(wp + ko + 32);
        const f32x4 b11 = *(const f32x4*)(wp + ko + 36);

#pragma unroll
        for (int kk = 0; kk < 2; ++kk) {
            s16x8 bh, bl;
            split8(kk ? b10 : b00, kk ? b11 : b01, bh, bl);
            const int ao = ko + kk * 32;
            const s16x8 a0h = *(const s16x8*)(ah0 + ao);
            const s16x8 a1h = *(const s16x8*)(ah1 + ao);
            const s16x8 a2h = *(const s16x8*)(ah2 + ao);
            const s16x8 a3h = *(const s16x8*)(ah3 + ao);
            const s16x8 a0l = *(const s16x8*)(al0 + ao);
            const s16x8 a1l = *(const s16x8*)(al1 + ao);
            const s16x8 a2l = *(const s16x8*)(al2 + ao);
            const s16x8 a3l = *(const s16x8*)(al3 + ao);
            acc0 = __builtin_amdgcn_mfma_f32_16x16x32_bf16(a0h, bh, acc0, 0, 0, 0);
            acc1 = __builtin_amdgcn_mfma_f32_16x16x32_bf16(a1h, bh, acc1, 0, 0, 0);
            acc2 = __builtin_amdgcn_mfma_f32_16x16x32_bf16(a2h, bh, acc2, 0, 0, 0);
            acc3 = __builtin_amdgcn_mfma_f32_16x16x32_bf16(a3h, bh, acc3, 0, 0, 0);
            acc0 = __builtin_amdgcn_mfma_f32_16x16x32_bf16(a0l, bh, acc0, 0, 0, 0);
            acc1 = __builtin_amdgcn_mfma_f32_16x16x32_bf16(a1l, bh, acc1, 0, 0, 0);
            acc2 = __builtin_amdgcn_mfma_f32_16x16x32_bf16(a2l, bh, acc2, 0, 0, 0);
            acc3 = __builtin_amdgcn_mfma_f32_16x16x32_bf16(a3l, bh, acc3, 0, 0, 0);
            acc0 = __builtin_amdgcn_mfma_f32_16x16x32_bf16(a0h, bl, acc0, 0, 0, 0);
            acc1 = __builtin_amdgcn_mfma_f32_16x16x32_bf16(a1h, bl, acc1, 0, 0, 0);
            acc2 = __builtin_amdgcn_mfma_f32_16x16x32_bf16(a2h, bl, acc2, 0, 0, 0);
            acc3 = __builtin_amdgcn_mfma_f32_16x16x32_bf16(a3h, bl, acc3, 0, 0, 0);
        }
    }

    float* op = outp + (size_t)ks * HSZ;
#pragma unroll
    for (int mt = 0; mt < 4; ++mt) {
        const f32x4 a = (mt == 0) ? acc0 : (mt == 1) ? acc1 : (mt == 2) ? acc2 : acc3;
#pragma unroll
        for (int r = 0; r < 4; ++r) {
            const int m = mt * 16 + lk8 * 4 + r;
            if (m < HROWS) op[(size_t)m * DIM + ncol] = a[r];
        }
    }
}

// ---------------------------------------------------------------------------
// P2 task vb in [0,216): reduce split-K partials -> bf16 hi/lo of h,
// plus fused attention-dot partials (per-wave, no atomics, deterministic).
// ---------------------------------------------------------------------------
__device__ __forceinline__ void p2_dev(const float* __restrict__ hpart,
                                       const float* __restrict__ wA,
                                       const float* __restrict__ wB,
                                       const float* __restrict__ wC,
                                       short* __restrict__ hbh, short* __restrict__ hbl,
                                       float* __restrict__ dotp,
                                       int vb, int tid)
{
    const int i   = vb * 1024 + tid * 4;
    const int col = i & (DIM - 1);
    f32x4 s = {0.f,0.f,0.f,0.f};
#pragma unroll
    for (int sl = 0; sl < SPLITK; ++sl) s += *(const f32x4*)(hpart + (size_t)sl * HSZ + i);

    s16x4 vh, vl;
#pragma unroll
    for (int j = 0; j < 4; ++j) {
        const short h = f2bf(s[j]);
        vh[j] = h; vl[j] = f2bf(s[j] - bf2f(h));
    }
    *(s16x4*)(hbh + i) = vh;
    *(s16x4*)(hbl + i) = vl;

    float a0=0,a1=0,a2=0,a3=0,a4=0,a5=0;
#pragma unroll
    for (int j = 0; j < 4; ++j) {
        const float sv = s[j];
        const int c = col + j;
        a0 += sv * wA[c]; a1 += sv * wA[DIM + c];
        a2 += sv * wB[c]; a3 += sv * wB[DIM + c];
        a4 += sv * wC[c]; a5 += sv * wC[DIM + c];
    }
#pragma unroll
    for (int off = 32; off > 0; off >>= 1) {
        a0 += __shfl_down(a0, off); a1 += __shfl_down(a1, off);
        a2 += __shfl_down(a2, off); a3 += __shfl_down(a3, off);
        a4 += __shfl_down(a4, off); a5 += __shfl_down(a5, off);
    }
    if ((tid & 63) == 0) {
        float* d = dotp + ((size_t)vb * 4 + (tid >> 6)) * 6;
        d[0]=a0; d[1]=a1; d[2]=a2; d[3]=a3; d[4]=a4; d[5]=a5;
    }
}

// ---------------------------------------------------------------------------
// P4 task vb in [0,216): reduce gemm2' split-K partials to f32 gsum.
// ---------------------------------------------------------------------------
__device__ __forceinline__ void p4_dev(const float* __restrict__ hpart,
                                       float* __restrict__ gsum, int vb, int tid)
{
    const int i = vb * 1024 + tid * 4;
    f32x4 s = {0.f,0.f,0.f,0.f};
#pragma unroll
    for (int sl = 0; sl < SPLITK; ++sl) s += *(const f32x4*)(hpart + (size_t)sl * HSZ + i);
    *(f32x4*)(gsum + i) = s;
}

// ---------------------------------------------------------------------------
// tmat: one 256-thread block. Reduce dot partials, build 54x54 T, write global.
// ---------------------------------------------------------------------------
__device__ void tmat_dev(const float* __restrict__ dotp, float* __restrict__ Tm, int tid)
{
    __shared__ float ds[324];
    __shared__ float Ts[54][54];
    __shared__ float ad0[5], adc[12], ar[6], fdot3[12], fdot5[12], ddot5[5];

    for (int x = tid; x < 324; x += 256) {
        const int r = x / 6, v = x % 6;
        float s = 0.f;
#pragma unroll
        for (int u = 0; u < 16; ++u) s += dotp[(size_t)(r * 16 + u) * 6 + v];
        ds[x] = s;
    }
    for (int i = tid; i < 54 * 54; i += 256) ((float*)Ts)[i] = 0.f;
    __syncthreads();

    if (tid < 12) {                       // level if
        const int p = tid;
        const float u = ds[(6+p)*6 + 0];
        const float ss = leaky(u + ds[(6+p)*6 + 1]);
        float sc[3], mx = ss;
#pragma unroll
        for (int j = 0; j < 3; ++j) { sc[j] = leaky(u + ds[(18+3*p+j)*6 + 1]); mx = fmaxf(mx, sc[j]); }
        float e0 = expf(ss - mx), s = e0, ec[3];
#pragma unroll
        for (int j = 0; j < 3; ++j) { ec[j] = expf(sc[j] - mx); s += ec[j]; }
        const float inv = 1.f / s;
        const float a0 = e0 * inv;
        float f3 = a0 * ds[(6+p)*6 + 3];
        float f5 = a0 * ds[(6+p)*6 + 5];
        Ts[6+p][6+p] = a0;
#pragma unroll
        for (int j = 0; j < 3; ++j) {
            const float a = ec[j] * inv;
            Ts[6+p][18+3*p+j] = a;
            f3 += a * ds[(18+3*p+j)*6 + 3];
            f5 += a * ds[(18+3*p+j)*6 + 5];
        }
        fdot3[p] = f3; fdot5[p] = f5;
    }
    __syncthreads();

    if (tid < 5) {                        // level fd
        const int p = tid;
        const int cstart[5] = {0,3,5,8,10};
        const int ccnt[5]   = {3,2,3,2,2};
        const float u = ds[(1+p)*6 + 2];
        const float ss = leaky(u + ds[(1+p)*6 + 3]);
        const int n = ccnt[p], c0 = cstart[p];
        float mx = ss, sc[3];
        for (int j = 0; j < n; ++j) { sc[j] = leaky(u + fdot3[c0+j]); mx = fmaxf(mx, sc[j]); }
        float e0 = expf(ss - mx), s = e0, ec[3];
        for (int j = 0; j < n; ++j) { ec[j] = expf(sc[j] - mx); s += ec[j]; }
        const float inv = 1.f / s;
        ad0[p] = e0 * inv;
        float d5 = ad0[p] * ds[(1+p)*6 + 5];
        for (int j = 0; j < n; ++j) {
            const float a = ec[j] * inv;
            adc[c0+j] = a;
            d5 += a * fdot5[c0+j];
        }
        ddot5[p] = d5;
    }
    __syncthreads();

    if (tid == 0) {                       // level dr
        const float u = ds[0*6 + 4];
        const float ss = leaky(u + ds[0*6 + 5]);
        float mx = ss, sc[5];
#pragma unroll
        for (int d = 0; d < 5; ++d) { sc[d] = leaky(u + ddot5[d]); mx = fmaxf(mx, sc[d]); }
        float e0 = expf(ss - mx), s = e0, ec[5];
#pragma unroll
        for (int d = 0; d < 5; ++d) { ec[d] = expf(sc[d] - mx); s += ec[d]; }
        const float inv = 1.f / s;
        ar[0] = e0 * inv;
#pragma unroll
        for (int d = 0; d < 5; ++d) ar[1+d] = ec[d] * inv;
    }
    for (int q = tid; q < 36; q += 256) Ts[18+q][18+q] = 1.f;
    __syncthreads();

    if (tid < 54) {                       // domain rows
        const int j = tid;
        const int cstart[5] = {0,3,5,8,10};
        const int ccnt[5]   = {3,2,3,2,2};
        for (int p = 0; p < 5; ++p) {
            float t = ad0[p] * ((j == 1+p) ? 1.f : 0.f);
            for (int c = cstart[p]; c < cstart[p] + ccnt[p]; ++c) t += adc[c] * Ts[6+c][j];
            Ts[1+p][j] = t;
        }
    }
    __syncthreads();
    if (tid < 54) {                       // root row
        float t = ar[0] * ((tid == 0) ? 1.f : 0.f);
        for (int d = 0; d < 5; ++d) t += ar[1+d] * Ts[1+d][tid];
        Ts[0][tid] = t;
    }
    __syncthreads();
    for (int i = tid; i < 54 * 54; i += 256) Tm[i] = ((float*)Ts)[i];
}

// ---------------------------------------------------------------------------
// P5 task t in [0,432): fused applyT + rope. h2 rows computed on the fly as
// T-row dot gsum-column (only the <=3 dense rows the chain needs + identity).
// ---------------------------------------------------------------------------
__device__ __forceinline__ void p5_dev(const float* __restrict__ gsum,
                                       const float* __restrict__ Tm,
                                       const float* __restrict__ er,
                                       const float* __restrict__ ei,
                                       short* __restrict__ xh, short* __restrict__ xl,
                                       float* __restrict__ xo, int last,
                                       int t, int tid)
{
    const int r  = t % 54;
    const int jt = t / 54;
    const int j  = jt * 256 + tid;          // 0..2047
    const int jj = j + 2048;
    constexpr int PF[12] = {0,0,0,1,1,2,2,2,3,3,4,4};

    int row1 = 0, row2 = 0;
    if (r >= 1 && r < 6)        { row1 = r; }
    else if (r >= 6 && r < 18)  { const int c = r - 6;      row1 = 1 + PF[c]; row2 = r; }
    else if (r >= 18)           { const int c = (r - 18)/3; row1 = 1 + PF[c]; row2 = 6 + c; }

    const float* T0 = Tm;
    const float* T1 = Tm + row1 * 54;
    const float* T2 = Tm + row2 * 54;

    float a0r=0,a0i=0,a1r=0,a1i=0,a2r=0,a2i=0;
#pragma unroll 6
    for (int k = 0; k < 54; ++k) {
        const float gr = gsum[(size_t)k * DIM + j];
        const float gi = gsum[(size_t)k * DIM + jj];
        const float t0 = T0[k], t1 = T1[k], t2 = T2[k];
        a0r += t0 * gr; a0i += t0 * gi;
        a1r += t1 * gr; a1i += t1 * gi;
        a2r += t2 * gr; a2i += t2 * gi;
    }

    const float rr = a0r, ri = a0i;
    float vr, vi, scale;
    if (r == 0) {
        vr = rr; vi = ri; scale = 1.f;
    } else {
        const float er0 = er[j], ei0 = ei[j];
        const float dr = a1r + rr * er0 - ri * ei0;
        const float di = a1i + rr * ei0 + ri * er0;
        if (r < 6) {
            vr = dr; vi = di; scale = 0.5f;
        } else {
            const float er1 = er[2048 + j], ei1 = ei[2048 + j];
            const float fr = a2r + dr * er1 - di * ei1;
            const float fi = a2i + dr * ei1 + di * er1;
            if (r < 18) {
                vr = fr; vi = fi; scale = 1.f / 3.f;
            } else {
                const float er2 = er[4096 + j], ei2 = ei[4096 + j];
                const float sr = gsum[(size_t)r * DIM + j];
                const float si = gsum[(size_t)r * DIM + jj];
                vr = sr + fr * er2 - fi * ei2;
                vi = si + fr * ei2 + fi * er2;
                scale = 0.25f;
            }
        }
    }
    vr *= scale; vi *= scale;
    if (last) {
        xo[(size_t)r * DIM + j]  = vr;
        xo[(size_t)r * DIM + jj] = vi;
    } else {
        const short h0 = f2bf(vr);
        xh[(size_t)r * DIM + j] = h0;
        xl[(size_t)r * DIM + j] = f2bf(vr - bf2f(h0));
        const short h1 = f2bf(vi);
        xh[(size_t)r * DIM + jj] = h1;
        xl[(size_t)r * DIM + jj] = f2bf(vi - bf2f(h1));
    }
}

// ---------------------------------------------------------------------------
// Cooperative mega-kernel: grid-stride over tasks; works for any nblk.
// ---------------------------------------------------------------------------
__global__ __launch_bounds__(256, 2) void mega_k(
    const float* __restrict__ ce,   const float* __restrict__ gatW,
    const float* __restrict__ attif,const float* __restrict__ attfd,
    const float* __restrict__ attdr,const float* __restrict__ metaW,
    const float* __restrict__ edge, float* __restrict__ out,
    float* hpart, float* gsum, float* dotp, float* Tm, float* er, float* ei,
    short* xbfh, short* xbfl, short* hbfh, short* hbfl, int nblk)
{
    cg::grid_group grid = cg::this_grid();
    const int bid = blockIdx.x;
    const int tid = threadIdx.x;

    for (int t = bid; t < 1024; t += nblk)
        prep_dev(ce, edge, xbfh, xbfl, hbfh, hbfl, er, ei, t, tid);
    grid.sync();

    for (int i = 0; i < 4; ++i) {
        // P1: hpart = x @ gat_W[i]^T (split-K)
        for (int t = bid; t < 512; t += nblk)
            gemm_dev(xbfh, xbfl, gatW + (size_t)i * DIM * DIM, hpart, t, tid);
        grid.sync();

        // P2: h reduce -> bf16 hi/lo + fused dot partials
        for (int t = bid; t < 216; t += nblk)
            p2_dev(hpart, attif + (size_t)i * 2 * DIM, attfd + (size_t)i * 2 * DIM,
                   attdr + (size_t)i * 2 * DIM, hbfh, hbfl, dotp, t, tid);
        grid.sync();

        // P3: hpart = h @ meta_W[i]^T (T not needed!); block 0 builds T
        for (int t = bid; t < 512; t += nblk)
            gemm_dev(hbfh, hbfl, metaW + (size_t)i * DIM * DIM, hpart, t, tid);
        if (bid == 0) tmat_dev(dotp, Tm, tid);
        grid.sync();

        // P4: gsum = reduce(hpart)
        for (int t = bid; t < 216; t += nblk)
            p4_dev(hpart, gsum, t, tid);
        grid.sync();

        // P5: fused h2 = T@gsum + rope chain -> x_next (or out)
        for (int t = bid; t < 432; t += nblk)
            p5_dev(gsum, Tm, er, ei, xbfh, xbfl, out, (i == 3) ? 1 : 0, t, tid);
        grid.sync();
    }
}

// ---------------------------------------------------------------------------
// Fallback wrappers (non-cooperative multi-launch path)
// ---------------------------------------------------------------------------
__global__ __launch_bounds__(256) void prep_g(const float* ce, const float* edge,
                                              short* xh, short* xl, short* hbh, short* hbl,
                                              float* er, float* ei)
{ prep_dev(ce, edge, xh, xl, hbh, hbl, er, ei, blockIdx.x, threadIdx.x); }

__global__ __launch_bounds__(256, 2) void gemm_g(const short* Ah, const short* Al,
                                                 const float* W, float* outp)
{ gemm_dev(Ah, Al, W, outp, blockIdx.x, threadIdx.x); }

__global__ __launch_bounds__(256) void p2_g(const float* hpart, const float* wA,
                                            const float* wB, const float* wC,
                                            short* hbh, short* hbl, float* dotp)
{ p2_dev(hpart, wA, wB, wC, hbh, hbl, dotp, blockIdx.x, threadIdx.x); }

__global__ __launch_bounds__(256) void tmat_g(const float* dotp, float* Tm)
{ tmat_dev(dotp, Tm, threadIdx.x); }

__global__ __launch_bounds__(256) void p4_g(const float* hpart, float* gsum)
{ p4_dev(hpart, gsum, blockIdx.x, threadIdx.x); }

__global__ __launch_bounds__(256) void p5_g(const float* gsum, const float* Tm,
                                            const float* er, const float* ei,
                                            short* xh, short* xl, float* xo, int last)
{ p5_dev(gsum, Tm, er, ei, xh, xl, xo, last, blockIdx.x, threadIdx.x); }

// ---------------------------------------------------------------------------
extern "C" void kernel_launch(void* const* d_in, const int* in_sizes, int n_in,
                              void* d_out, int out_size, void* d_ws, size_t ws_size,
                              hipStream_t stream)
{
    const float* ce    = (const float*)d_in[0];
    const float* gatW  = (const float*)d_in[1];
    const float* attif = (const float*)d_in[2];
    const float* attfd = (const float*)d_in[3];
    const float* attdr = (const float*)d_in[4];
    const float* metaW = (const float*)d_in[5];
    const float* edge  = (const float*)d_in[6];
    float* out = (float*)d_out;

    char* w = (char*)d_ws;
    float* hpart = (float*)w;   w += (size_t)SPLITK * HSZ * 4;   // 7.08 MB
    float* gsum  = (float*)w;   w += (size_t)HSZ * 4;            // 884 KB
    float* dotp  = (float*)w;   w += 6144 * 4;                   // 864*6 used
    float* Tm    = (float*)w;   w += 16384;
    float* er    = (float*)w;   w += 3 * 2048 * 4;
    float* ei    = (float*)w;   w += 3 * 2048 * 4;
    short* xbfh  = (short*)w;   w += (size_t)64 * DIM * 2;       // 512 KB each
    short* xbfl  = (short*)w;   w += (size_t)64 * DIM * 2;
    short* hbfh  = (short*)w;   w += (size_t)64 * DIM * 2;
    short* hbfl  = (short*)w;   w += (size_t)64 * DIM * 2;

    // --- decide cooperative path deterministically ---
    int dev = 0;
    hipGetDevice(&dev);
    int coop = 0;
    hipDeviceGetAttribute(&coop, hipDeviceAttributeCooperativeLaunch, dev);
    int cus = 0;
    hipDeviceGetAttribute(&cus, hipDeviceAttributeMultiprocessorCount, dev);
    int occ = 0;
    hipError_t oe = hipOccupancyMaxActiveBlocksPerMultiprocessor(&occ, mega_k, 256, 0);

    hipError_t le = hipErrorUnknown;
    if (coop && oe == hipSuccess && occ >= 1 && cus > 0) {
        int nblk = occ * cus;
        if (nblk > 512) nblk = 512;
        void* args[] = { (void*)&ce, (void*)&gatW, (void*)&attif, (void*)&attfd,
                         (void*)&attdr, (void*)&metaW, (void*)&edge, (void*)&out,
                         (void*)&hpart, (void*)&gsum, (void*)&dotp, (void*)&Tm,
                         (void*)&er, (void*)&ei,
                         (void*)&xbfh, (void*)&xbfl, (void*)&hbfh, (void*)&hbfl,
                         (void*)&nblk };
        le = hipLaunchCooperativeKernel(mega_k, dim3(nblk), dim3(256), args, 0, stream);
    }

    if (le != hipSuccess) {
        // --- fallback: multi-launch path (same device code) ---
        hipLaunchKernelGGL(prep_g, dim3(1024), dim3(256), 0, stream,
                           ce, edge, xbfh, xbfl, hbfh, hbfl, er, ei);
        for (int i = 0; i < 4; ++i) {
            hipLaunchKernelGGL(gemm_g, dim3(512), dim3(256), 0, stream,
                               xbfh, xbfl, gatW + (size_t)i * DIM * DIM, hpart);
            hipLaunchKernelGGL(p2_g, dim3(216), dim3(256), 0, stream,
                               hpart, attif + (size_t)i * 2 * DIM, attfd + (size_t)i * 2 * DIM,
                               attdr + (size_t)i * 2 * DIM, hbfh, hbfl, dotp);
            hipLaunchKernelGGL(tmat_g, dim3(1), dim3(256), 0, stream, dotp, Tm);
            hipLaunchKernelGGL(gemm_g, dim3(512), dim3(256), 0, stream,
                               hbfh, hbfl, metaW + (size_t)i * DIM * DIM, hpart);
            hipLaunchKernelGGL(p4_g, dim3(216), dim3(256), 0, stream, hpart, gsum);
            hipLaunchKernelGGL(p5_g, dim3(432), dim3(256), 0, stream,
                               gsum, Tm, er, ei, xbfh, xbfl, out, (i == 3) ? 1 : 0);
        }
    }
}

// Round 7
// 410.414 us; speedup vs baseline: 2.6797x; 2.6797x over previous
//
#include <hip/hip_runtime.h>
#include <hip/hip_bf16.h>

#define DIM 4096
#define HROWS 54
#define HSZ (54 * 4096)
#define SPLITK 8
#define KSLICE 512

typedef __attribute__((ext_vector_type(4))) float  f32x4;
typedef __attribute__((ext_vector_type(8))) short  s16x8;
typedef __attribute__((ext_vector_type(4))) short  s16x4;

__device__ __forceinline__ short f2bf(float f) {
    union { __hip_bfloat16 h; short s; } u;
    u.h = __float2bfloat16(f);
    return u.s;
}
__device__ __forceinline__ float bf2f(short s) {
    union { __hip_bfloat16 h; short s; } u;
    u.s = s;
    return __bfloat162float(u.h);
}
__device__ __forceinline__ float leaky(float x) { return x > 0.f ? x : 0.01f * x; }

__device__ __forceinline__ void split8(const f32x4& c0, const f32x4& c1,
                                       s16x8& h, s16x8& l) {
#pragma unroll
    for (int j = 0; j < 4; ++j) {
        short h0 = f2bf(c0[j]); h[j]     = h0; l[j]     = f2bf(c0[j] - bf2f(h0));
        short h1 = f2bf(c1[j]); h[4 + j] = h1; l[4 + j] = f2bf(c1[j] - bf2f(h1));
    }
}

// ---------------------------------------------------------------------------
// prep: bf16 split of concept_embed (padded to 64 rows), zero pads, trig tables
// ---------------------------------------------------------------------------
__global__ __launch_bounds__(256) void prep_g(const float* __restrict__ ce,
                                              const float* __restrict__ edge,
                                              short* __restrict__ xh, short* __restrict__ xl,
                                              short* __restrict__ hbh, short* __restrict__ hbl,
                                              float* __restrict__ er, float* __restrict__ ei)
{
    const int idx = blockIdx.x * 256 + threadIdx.x;
    const int row = idx >> 12;
    if (row < HROWS) {
        const float v = ce[idx];
        const short h = f2bf(v);
        xh[idx] = h; xl[idx] = f2bf(v - bf2f(h));
    } else {
        xh[idx] = 0; xl[idx] = 0; hbh[idx] = 0; hbl[idx] = 0;
    }
    if (idx < 3 * 2048) {
        const float e = edge[idx];
        er[idx] = cosf(e);
        ei[idx] = sinf(e);
    }
}

// ---------------------------------------------------------------------------
// GEMM v4: out[m,n] = sum_k A[m,k]*W[n,k]. A bf16 hi/lo [64][4096] (L2),
// W f32 streamed from HBM with EXPLICIT 2-iteration-lookahead register
// pipeline (3 named sets) so ~12 W loads stay in flight per wave.
// Barrier-free, LDS-free. grid = 64 nb x 8 ks = 512 blocks.
// ---------------------------------------------------------------------------
__global__ __launch_bounds__(256, 2) void gemm_g(const short* __restrict__ Ah,
                                                 const short* __restrict__ Al,
                                                 const float* __restrict__ W,
                                                 float* __restrict__ outp)
{
    const int tid  = threadIdx.x;
    const int lane = tid & 63;
    const int wv   = tid >> 6;
    const int nb   = blockIdx.x & 63;
    const int ks   = blockIdx.x >> 6;
    const int l15  = lane & 15;
    const int lk8  = lane >> 4;

    const int ncol = nb * 64 + wv * 16 + l15;
    const int k0   = ks * KSLICE + lk8 * 8;
    const float* wp = W + (size_t)ncol * DIM + k0;

    const short* ah0 = Ah + (size_t)(0 * 16 + l15) * DIM + k0;
    const short* ah1 = Ah + (size_t)(1 * 16 + l15) * DIM + k0;
    const short* ah2 = Ah + (size_t)(2 * 16 + l15) * DIM + k0;
    const short* ah3 = Ah + (size_t)(3 * 16 + l15) * DIM + k0;
    const short* al0 = Al + (size_t)(0 * 16 + l15) * DIM + k0;
    const short* al1 = Al + (size_t)(1 * 16 + l15) * DIM + k0;
    const short* al2 = Al + (size_t)(2 * 16 + l15) * DIM + k0;
    const short* al3 = Al + (size_t)(3 * 16 + l15) * DIM + k0;

    f32x4 acc0 = {0.f,0.f,0.f,0.f}, acc1 = {0.f,0.f,0.f,0.f};
    f32x4 acc2 = {0.f,0.f,0.f,0.f}, acc3 = {0.f,0.f,0.f,0.f};

    f32x4 wa0, wa1, wa2, wa3;
    f32x4 wb0, wb1, wb2, wb3;
    f32x4 wc0, wc1, wc2, wc3;

#define WLOAD(S0,S1,S2,S3,KB) do {                                           \
    S0 = *(const f32x4*)(wp + (KB)*64);                                      \
    S1 = *(const f32x4*)(wp + (KB)*64 + 4);                                  \
    S2 = *(const f32x4*)(wp + (KB)*64 + 32);                                 \
    S3 = *(const f32x4*)(wp + (KB)*64 + 36); } while (0)

#define MFMA12(BH,BL,A0H,A1H,A2H,A3H,A0L,A1L,A2L,A3L) do {                   \
    acc0 = __builtin_amdgcn_mfma_f32_16x16x32_bf16(A0H, BH, acc0, 0, 0, 0);  \
    acc1 = __builtin_amdgcn_mfma_f32_16x16x32_bf16(A1H, BH, acc1, 0, 0, 0);  \
    acc2 = __builtin_amdgcn_mfma_f32_16x16x32_bf16(A2H, BH, acc2, 0, 0, 0);  \
    acc3 = __builtin_amdgcn_mfma_f32_16x16x32_bf16(A3H, BH, acc3, 0, 0, 0);  \
    acc0 = __builtin_amdgcn_mfma_f32_16x16x32_bf16(A0L, BH, acc0, 0, 0, 0);  \
    acc1 = __builtin_amdgcn_mfma_f32_16x16x32_bf16(A1L, BH, acc1, 0, 0, 0);  \
    acc2 = __builtin_amdgcn_mfma_f32_16x16x32_bf16(A2L, BH, acc2, 0, 0, 0);  \
    acc3 = __builtin_amdgcn_mfma_f32_16x16x32_bf16(A3L, BH, acc3, 0, 0, 0);  \
    acc0 = __builtin_amdgcn_mfma_f32_16x16x32_bf16(A0H, BL, acc0, 0, 0, 0);  \
    acc1 = __builtin_amdgcn_mfma_f32_16x16x32_bf16(A1H, BL, acc1, 0, 0, 0);  \
    acc2 = __builtin_amdgcn_mfma_f32_16x16x32_bf16(A2H, BL, acc2, 0, 0, 0);  \
    acc3 = __builtin_amdgcn_mfma_f32_16x16x32_bf16(A3H, BL, acc3, 0, 0, 0); } while (0)

#define WSTEP(S0,S1,S2,S3,KB) do {                                           \
    const int ko = (KB) * 64;                                                \
    {   const s16x8 a0h = *(const s16x8*)(ah0 + ko);                         \
        const s16x8 a1h = *(const s16x8*)(ah1 + ko);                         \
        const s16x8 a2h = *(const s16x8*)(ah2 + ko);                         \
        const s16x8 a3h = *(const s16x8*)(ah3 + ko);                         \
        const s16x8 a0l = *(const s16x8*)(al0 + ko);                         \
        const s16x8 a1l = *(const s16x8*)(al1 + ko);                         \
        const s16x8 a2l = *(const s16x8*)(al2 + ko);                         \
        const s16x8 a3l = *(const s16x8*)(al3 + ko);                         \
        s16x8 bh, bl;  split8(S0, S1, bh, bl);                               \
        MFMA12(bh, bl, a0h, a1h, a2h, a3h, a0l, a1l, a2l, a3l); }            \
    {   const s16x8 a0h = *(const s16x8*)(ah0 + ko + 32);                    \
        const s16x8 a1h = *(const s16x8*)(ah1 + ko + 32);                    \
        const s16x8 a2h = *(const s16x8*)(ah2 + ko + 32);                    \
        const s16x8 a3h = *(const s16x8*)(ah3 + ko + 32);                    \
        const s16x8 a0l = *(const s16x8*)(al0 + ko + 32);                    \
        const s16x8 a1l = *(const s16x8*)(al1 + ko + 32);                    \
        const s16x8 a2l = *(const s16x8*)(al2 + ko + 32);                    \
        const s16x8 a3l = *(const s16x8*)(al3 + ko + 32);                    \
        s16x8 bh, bl;  split8(S2, S3, bh, bl);                               \
        MFMA12(bh, bl, a0h, a1h, a2h, a3h, a0l, a1l, a2l, a3l); } } while (0)

    // software pipeline, lookahead 2
    WLOAD(wa0, wa1, wa2, wa3, 0);
    WLOAD(wb0, wb1, wb2, wb3, 1);
    WLOAD(wc0, wc1, wc2, wc3, 2);  WSTEP(wa0, wa1, wa2, wa3, 0);
    WLOAD(wa0, wa1, wa2, wa3, 3);  WSTEP(wb0, wb1, wb2, wb3, 1);
    WLOAD(wb0, wb1, wb2, wb3, 4);  WSTEP(wc0, wc1, wc2, wc3, 2);
    WLOAD(wc0, wc1, wc2, wc3, 5);  WSTEP(wa0, wa1, wa2, wa3, 3);
    WLOAD(wa0, wa1, wa2, wa3, 6);  WSTEP(wb0, wb1, wb2, wb3, 4);
    WLOAD(wb0, wb1, wb2, wb3, 7);  WSTEP(wc0, wc1, wc2, wc3, 5);
    WSTEP(wa0, wa1, wa2, wa3, 6);
    WSTEP(wb0, wb1, wb2, wb3, 7);

#undef WLOAD
#undef MFMA12
#undef WSTEP

    float* op = outp + (size_t)ks * HSZ;
#pragma unroll
    for (int mt = 0; mt < 4; ++mt) {
        const f32x4 a = (mt == 0) ? acc0 : (mt == 1) ? acc1 : (mt == 2) ? acc2 : acc3;
#pragma unroll
        for (int r = 0; r < 4; ++r) {
            const int m = mt * 16 + lk8 * 4 + r;
            if (m < HROWS) op[(size_t)m * DIM + ncol] = a[r];
        }
    }
}

// ---------------------------------------------------------------------------
// p2: reduce split-K partials -> bf16 hi/lo of h + fused attention-dot partials
// ---------------------------------------------------------------------------
__global__ __launch_bounds__(256) void p2_g(const float* __restrict__ hpart,
                                            const float* __restrict__ wA,
                                            const float* __restrict__ wB,
                                            const float* __restrict__ wC,
                                            short* __restrict__ hbh, short* __restrict__ hbl,
                                            float* __restrict__ dotp)
{
    const int vb  = blockIdx.x;          // 0..215
    const int tid = threadIdx.x;
    const int i   = vb * 1024 + tid * 4;
    const int col = i & (DIM - 1);
    f32x4 s = {0.f,0.f,0.f,0.f};
#pragma unroll
    for (int sl = 0; sl < SPLITK; ++sl) s += *(const f32x4*)(hpart + (size_t)sl * HSZ + i);

    s16x4 vh, vl;
#pragma unroll
    for (int j = 0; j < 4; ++j) {
        const short h = f2bf(s[j]);
        vh[j] = h; vl[j] = f2bf(s[j] - bf2f(h));
    }
    *(s16x4*)(hbh + i) = vh;
    *(s16x4*)(hbl + i) = vl;

    float a0=0,a1=0,a2=0,a3=0,a4=0,a5=0;
#pragma unroll
    for (int j = 0; j < 4; ++j) {
        const float sv = s[j];
        const int c = col + j;
        a0 += sv * wA[c]; a1 += sv * wA[DIM + c];
        a2 += sv * wB[c]; a3 += sv * wB[DIM + c];
        a4 += sv * wC[c]; a5 += sv * wC[DIM + c];
    }
#pragma unroll
    for (int off = 32; off > 0; off >>= 1) {
        a0 += __shfl_down(a0, off); a1 += __shfl_down(a1, off);
        a2 += __shfl_down(a2, off); a3 += __shfl_down(a3, off);
        a4 += __shfl_down(a4, off); a5 += __shfl_down(a5, off);
    }
    if ((tid & 63) == 0) {
        float* d = dotp + ((size_t)vb * 4 + (tid >> 6)) * 6;
        d[0]=a0; d[1]=a1; d[2]=a2; d[3]=a3; d[4]=a4; d[5]=a5;
    }
}

// ---------------------------------------------------------------------------
// p4: reduce gemm2 split-K partials to f32 gsum
// ---------------------------------------------------------------------------
__global__ __launch_bounds__(256) void p4_g(const float* __restrict__ hpart,
                                            float* __restrict__ gsum)
{
    const int i = blockIdx.x * 1024 + threadIdx.x * 4;
    f32x4 s = {0.f,0.f,0.f,0.f};
#pragma unroll
    for (int sl = 0; sl < SPLITK; ++sl) s += *(const f32x4*)(hpart + (size_t)sl * HSZ + i);
    *(f32x4*)(gsum + i) = s;
}

// ---------------------------------------------------------------------------
// tmat: one block. Reduce dot partials, build 54x54 mixing matrix T.
// ---------------------------------------------------------------------------
__global__ __launch_bounds__(256) void tmat_g(const float* __restrict__ dotp,
                                              float* __restrict__ Tm)
{
    const int tid = threadIdx.x;
    __shared__ float ds[324];
    __shared__ float Ts[54][54];
    __shared__ float ad0[5], adc[12], ar[6], fdot3[12], fdot5[12], ddot5[5];

    for (int x = tid; x < 324; x += 256) {
        const int r = x / 6, v = x % 6;
        float s = 0.f;
#pragma unroll
        for (int u = 0; u < 16; ++u) s += dotp[(size_t)(r * 16 + u) * 6 + v];
        ds[x] = s;
    }
    for (int i = tid; i < 54 * 54; i += 256) ((float*)Ts)[i] = 0.f;
    __syncthreads();

    if (tid < 12) {                       // level if
        const int p = tid;
        const float u = ds[(6+p)*6 + 0];
        const float ss = leaky(u + ds[(6+p)*6 + 1]);
        float sc[3], mx = ss;
#pragma unroll
        for (int j = 0; j < 3; ++j) { sc[j] = leaky(u + ds[(18+3*p+j)*6 + 1]); mx = fmaxf(mx, sc[j]); }
        float e0 = expf(ss - mx), s = e0, ec[3];
#pragma unroll
        for (int j = 0; j < 3; ++j) { ec[j] = expf(sc[j] - mx); s += ec[j]; }
        const float inv = 1.f / s;
        const float a0 = e0 * inv;
        float f3 = a0 * ds[(6+p)*6 + 3];
        float f5 = a0 * ds[(6+p)*6 + 5];
        Ts[6+p][6+p] = a0;
#pragma unroll
        for (int j = 0; j < 3; ++j) {
            const float a = ec[j] * inv;
            Ts[6+p][18+3*p+j] = a;
            f3 += a * ds[(18+3*p+j)*6 + 3];
            f5 += a * ds[(18+3*p+j)*6 + 5];
        }
        fdot3[p] = f3; fdot5[p] = f5;
    }
    __syncthreads();

    if (tid < 5) {                        // level fd
        const int p = tid;
        const int cstart[5] = {0,3,5,8,10};
        const int ccnt[5]   = {3,2,3,2,2};
        const float u = ds[(1+p)*6 + 2];
        const float ss = leaky(u + ds[(1+p)*6 + 3]);
        const int n = ccnt[p], c0 = cstart[p];
        float mx = ss, sc[3];
        for (int j = 0; j < n; ++j) { sc[j] = leaky(u + fdot3[c0+j]); mx = fmaxf(mx, sc[j]); }
        float e0 = expf(ss - mx), s = e0, ec[3];
        for (int j = 0; j < n; ++j) { ec[j] = expf(sc[j] - mx); s += ec[j]; }
        const float inv = 1.f / s;
        ad0[p] = e0 * inv;
        float d5 = ad0[p] * ds[(1+p)*6 + 5];
        for (int j = 0; j < n; ++j) {
            const float a = ec[j] * inv;
            adc[c0+j] = a;
            d5 += a * fdot5[c0+j];
        }
        ddot5[p] = d5;
    }
    __syncthreads();

    if (tid == 0) {                       // level dr
        const float u = ds[0*6 + 4];
        const float ss = leaky(u + ds[0*6 + 5]);
        float mx = ss, sc[5];
#pragma unroll
        for (int d = 0; d < 5; ++d) { sc[d] = leaky(u + ddot5[d]); mx = fmaxf(mx, sc[d]); }
        float e0 = expf(ss - mx), s = e0, ec[5];
#pragma unroll
        for (int d = 0; d < 5; ++d) { ec[d] = expf(sc[d] - mx); s += ec[d]; }
        const float inv = 1.f / s;
        ar[0] = e0 * inv;
#pragma unroll
        for (int d = 0; d < 5; ++d) ar[1+d] = ec[d] * inv;
    }
    for (int q = tid; q < 36; q += 256) Ts[18+q][18+q] = 1.f;
    __syncthreads();

    if (tid < 54) {                       // domain rows
        const int j = tid;
        const int cstart[5] = {0,3,5,8,10};
        const int ccnt[5]   = {3,2,3,2,2};
        for (int p = 0; p < 5; ++p) {
            float t = ad0[p] * ((j == 1+p) ? 1.f : 0.f);
            for (int c = cstart[p]; c < cstart[p] + ccnt[p]; ++c) t += adc[c] * Ts[6+c][j];
            Ts[1+p][j] = t;
        }
    }
    __syncthreads();
    if (tid < 54) {                       // root row
        float t = ar[0] * ((tid == 0) ? 1.f : 0.f);
        for (int d = 0; d < 5; ++d) t += ar[1+d] * Ts[1+d][tid];
        Ts[0][tid] = t;
    }
    __syncthreads();
    for (int i = tid; i < 54 * 54; i += 256) Tm[i] = ((float*)Ts)[i];
}

// ---------------------------------------------------------------------------
// p5: fused applyT + rope. h2 rows on the fly (<=3 T-row dots per thread).
// grid (432): t = (jt 0..7) * 54 + r.
// ---------------------------------------------------------------------------
__global__ __launch_bounds__(256) void p5_g(const float* __restrict__ gsum,
                                            const float* __restrict__ Tm,
                                            const float* __restrict__ er,
                                            const float* __restrict__ ei,
                                            short* __restrict__ xh, short* __restrict__ xl,
                                            float* __restrict__ xo, int last)
{
    const int t   = blockIdx.x;
    const int tid = threadIdx.x;
    const int r  = t % 54;
    const int jt = t / 54;
    const int j  = jt * 256 + tid;          // 0..2047
    const int jj = j + 2048;
    constexpr int PF[12] = {0,0,0,1,1,2,2,2,3,3,4,4};

    int row1 = 0, row2 = 0;
    if (r >= 1 && r < 6)        { row1 = r; }
    else if (r >= 6 && r < 18)  { const int c = r - 6;      row1 = 1 + PF[c]; row2 = r; }
    else if (r >= 18)           { const int c = (r - 18)/3; row1 = 1 + PF[c]; row2 = 6 + c; }

    const float* T0 = Tm;
    const float* T1 = Tm + row1 * 54;
    const float* T2 = Tm + row2 * 54;

    float a0r=0,a0i=0,a1r=0,a1i=0,a2r=0,a2i=0;
#pragma unroll 6
    for (int k = 0; k < 54; ++k) {
        const float gr = gsum[(size_t)k * DIM + j];
        const float gi = gsum[(size_t)k * DIM + jj];
        const float t0 = T0[k], t1 = T1[k], t2 = T2[k];
        a0r += t0 * gr; a0i += t0 * gi;
        a1r += t1 * gr; a1i += t1 * gi;
        a2r += t2 * gr; a2i += t2 * gi;
    }

    const float rr = a0r, ri = a0i;
    float vr, vi, scale;
    if (r == 0) {
        vr = rr; vi = ri; scale = 1.f;
    } else {
        const float er0 = er[j], ei0 = ei[j];
        const float dr = a1r + rr * er0 - ri * ei0;
        const float di = a1i + rr * ei0 + ri * er0;
        if (r < 6) {
            vr = dr; vi = di; scale = 0.5f;
        } else {
            const float er1 = er[2048 + j], ei1 = ei[2048 + j];
            const float fr = a2r + dr * er1 - di * ei1;
            const float fi = a2i + dr * ei1 + di * er1;
            if (r < 18) {
                vr = fr; vi = fi; scale = 1.f / 3.f;
            } else {
                const float er2 = er[4096 + j], ei2 = ei[4096 + j];
                const float sr = gsum[(size_t)r * DIM + j];
                const float si = gsum[(size_t)r * DIM + jj];
                vr = sr + fr * er2 - fi * ei2;
                vi = si + fr * ei2 + fi * er2;
                scale = 0.25f;
            }
        }
    }
    vr *= scale; vi *= scale;
    if (last) {
        xo[(size_t)r * DIM + j]  = vr;
        xo[(size_t)r * DIM + jj] = vi;
    } else {
        const short h0 = f2bf(vr);
        xh[(size_t)r * DIM + j] = h0;
        xl[(size_t)r * DIM + j] = f2bf(vr - bf2f(h0));
        const short h1 = f2bf(vi);
        xh[(size_t)r * DIM + jj] = h1;
        xl[(size_t)r * DIM + jj] = f2bf(vi - bf2f(h1));
    }
}

// ---------------------------------------------------------------------------
extern "C" void kernel_launch(void* const* d_in, const int* in_sizes, int n_in,
                              void* d_out, int out_size, void* d_ws, size_t ws_size,
                              hipStream_t stream)
{
    const float* ce    = (const float*)d_in[0];
    const float* gatW  = (const float*)d_in[1];
    const float* attif = (const float*)d_in[2];
    const float* attfd = (const float*)d_in[3];
    const float* attdr = (const float*)d_in[4];
    const float* metaW = (const float*)d_in[5];
    const float* edge  = (const float*)d_in[6];
    float* out = (float*)d_out;

    char* w = (char*)d_ws;
    float* hpart = (float*)w;   w += (size_t)SPLITK * HSZ * 4;   // 7.08 MB
    float* gsum  = (float*)w;   w += (size_t)HSZ * 4;            // 884 KB
    float* dotp  = (float*)w;   w += 6144 * 4;                   // 864*6 used
    float* Tm    = (float*)w;   w += 16384;
    float* er    = (float*)w;   w += 3 * 2048 * 4;
    float* ei    = (float*)w;   w += 3 * 2048 * 4;
    short* xbfh  = (short*)w;   w += (size_t)64 * DIM * 2;       // 512 KB each
    short* xbfl  = (short*)w;   w += (size_t)64 * DIM * 2;
    short* hbfh  = (short*)w;   w += (size_t)64 * DIM * 2;
    short* hbfl  = (short*)w;   w += (size_t)64 * DIM * 2;

    hipLaunchKernelGGL(prep_g, dim3(1024), dim3(256), 0, stream,
                       ce, edge, xbfh, xbfl, hbfh, hbfl, er, ei);

    for (int i = 0; i < 4; ++i) {
        hipLaunchKernelGGL(gemm_g, dim3(512), dim3(256), 0, stream,
                           xbfh, xbfl, gatW + (size_t)i * DIM * DIM, hpart);
        hipLaunchKernelGGL(p2_g, dim3(216), dim3(256), 0, stream,
                           hpart, attif + (size_t)i * 2 * DIM, attfd + (size_t)i * 2 * DIM,
                           attdr + (size_t)i * 2 * DIM, hbfh, hbfl, dotp);
        hipLaunchKernelGGL(tmat_g, dim3(1), dim3(256), 0, stream, dotp, Tm);
        hipLaunchKernelGGL(gemm_g, dim3(512), dim3(256), 0, stream,
                           hbfh, hbfl, metaW + (size_t)i * DIM * DIM, hpart);
        hipLaunchKernelGGL(p4_g, dim3(216), dim3(256), 0, stream, hpart, gsum);
        hipLaunchKernelGGL(p5_g, dim3(432), dim3(256), 0, stream,
                           gsum, Tm, er, ei, xbfh, xbfl, out, (i == 3) ? 1 : 0);
    }
}